// Round 6
// baseline (171.860 us; speedup 1.0000x reference)
//
#include <hip/hip_runtime.h>
#include <stdint.h>

typedef __bf16 bf16x8 __attribute__((ext_vector_type(8)));
typedef float f32x4 __attribute__((ext_vector_type(4)));
typedef unsigned short u16x8 __attribute__((ext_vector_type(8)));

__device__ __forceinline__ unsigned short f2bf(float f) {
  uint32_t u = __builtin_bit_cast(uint32_t, f);
  u += 0x7FFFu + ((u >> 16) & 1u);   // RNE
  return (unsigned short)(u >> 16);
}
__device__ __forceinline__ float bf2f(unsigned short h) {
  uint32_t u = ((uint32_t)h) << 16;
  return __builtin_bit_cast(float, u);
}

__device__ __forceinline__ void gload_lds16(const void* g, void* l) {
  __builtin_amdgcn_global_load_lds(
      (const __attribute__((address_space(1))) uint32_t*)g,
      (__attribute__((address_space(3))) uint32_t*)l,
      16, 0, 0);
}

// w: [K][N] f32  ->  wt: [N][K] bf16  (transpose + convert)
__global__ __launch_bounds__(256) void k_cvt_wT(const float* __restrict__ w,
                                                unsigned short* __restrict__ wt, int K, int N) {
  int total = K * N;
  int stride = gridDim.x * blockDim.x;
  for (int i = blockIdx.x * blockDim.x + threadIdx.x; i < total; i += stride) {
    int n = i / K;
    int k = i - n * K;
    wt[i] = f2bf(w[(size_t)k * N + n]);
  }
}

// ---- GEMM1 fused: C[M,1536] = bf16(X[M,512]) * wqT[1536,512]^T, qkv epilogue
// 256x256 tile, BK=64, 8 waves (2Mx4N, wave-tile 128x64).
// A is reg-staged DIRECTLY from f32 X (f2bf in-kernel: cvt_x pass eliminated):
//   phase0 issues 8 float4 loads (tile kt+1), phase1 issues B's 4 global_load_lds,
//   phases 2/3 convert+ds_write A after vmcnt(4) (B stays in flight; T14).
// LDS: 2 bufs x (A 32KB + B 32KB) = 128KB. Per K-tile: 4 phases, each
//   {4x ds_read A-pair [+8x B reads at p0] ; staging slice ; s_barrier ;
//    setprio(1) 16 MFMA setprio(0) ; s_barrier}  (m201-style interleave),
// then tile-end vmcnt(0)+lgkmcnt(0)+barrier.
// A swizzle: both-sides XOR on ds_write/ds_read (chunk ^= row&7).
// B swizzle: pre-swizzled global source + XOR'd ds_read (linear gload dest).
__global__ __launch_bounds__(512, 2) void k_g1(
    const float* __restrict__ X,
    const unsigned short* __restrict__ Bt,
    const float* __restrict__ bias,
    const float* __restrict__ brw,
    unsigned short* __restrict__ oq,
    unsigned short* __restrict__ okk,
    unsigned short* __restrict__ ov,
    int Ntiles) {
  __shared__ __align__(128) char lds[131072];
  // A bufs: [0,32K),[32K,64K); B bufs: [64K,96K),[96K,128K)

  int cpx = gridDim.x >> 3;
  int bid = (blockIdx.x & 7) * cpx + (blockIdx.x >> 3);
  int bm = bid / Ntiles;
  int bn = bid - bm * Ntiles;
  int row0 = bm << 8;
  int col0 = bn << 8;
  int t = threadIdx.x;
  int lane = t & 63;
  int w = t >> 6;
  int wm = w >> 2;
  int wn = w & 3;
  int lr = lane & 15;
  int lk = lane >> 4;

  const float* Xb = X + (size_t)row0 * 512;
  const unsigned short* Bb = Bt + (size_t)col0 * 512;

  // per-thread staging geometry: chunk c = i*512 + t (i<4), row=c>>3, slot=c&7
  int srow = t >> 3;          // rows srow, srow+64, srow+128, srow+192
  int sslot = t & 7;

  f32x4 acc[8][4];
#pragma unroll
  for (int i = 0; i < 8; ++i)
#pragma unroll
    for (int j = 0; j < 4; ++j) acc[i][j] = f32x4{0.f, 0.f, 0.f, 0.f};

  f32x4 ar[8];  // staged A (f32), 2 float4 per chunk

  auto loadA = [&](int kt) {
#pragma unroll
    for (int i = 0; i < 4; ++i) {
      int row = srow + (i << 6);
      const float* src = Xb + (size_t)row * 512 + (kt << 6) + (sslot << 3);
      ar[2 * i] = *reinterpret_cast<const f32x4*>(src);
      ar[2 * i + 1] = *reinterpret_cast<const f32x4*>(src + 4);
    }
  };
  auto writeA = [&](int kt, int half) {
    char* buf = lds + ((kt & 1) << 15);
#pragma unroll
    for (int i = half * 2; i < half * 2 + 2; ++i) {
      int row = srow + (i << 6);
      u16x8 o;
#pragma unroll
      for (int e = 0; e < 4; ++e) {
        o[e] = f2bf(ar[2 * i][e]);
        o[4 + e] = f2bf(ar[2 * i + 1][e]);
      }
      *reinterpret_cast<u16x8*>(buf + (row << 7) + ((sslot ^ (row & 7)) << 4)) = o;
    }
  };
  auto stageB = [&](int kt) {
    char* buf = lds + 65536 + ((kt & 1) << 15);
#pragma unroll
    for (int i = 0; i < 4; ++i) {
      int row = srow + (i << 6);
      int gk = (kt << 6) + ((sslot ^ (row & 7)) << 3);
      gload_lds16(Bb + (size_t)row * 512 + gk,
                  buf + (row << 7) + (sslot << 4));
    }
  };

  // ---- prologue: stage tile 0
  loadA(0);
  stageB(0);
  asm volatile("s_waitcnt vmcnt(4)" ::: "memory");  // A(0) loads done
  writeA(0, 0);
  writeA(0, 1);
  asm volatile("s_waitcnt vmcnt(0) lgkmcnt(0)" ::: "memory");
  __builtin_amdgcn_s_barrier();

#pragma unroll 1
  for (int kt = 0; kt < 8; ++kt) {
    const char* Abuf = lds + ((kt & 1) << 15);
    const char* Bbuf = lds + 65536 + ((kt & 1) << 15);
    bool pf = kt < 7;
    bf16x8 bfr[8];
#pragma unroll
    for (int p = 0; p < 4; ++p) {
      bf16x8 af[4];
#pragma unroll
      for (int m2 = 0; m2 < 2; ++m2)
#pragma unroll
        for (int ks = 0; ks < 2; ++ks) {
          int r = (wm << 7) + (((p << 1) + m2) << 4) + lr;
          int ch = (ks << 2) + lk;
          af[(m2 << 1) + ks] =
              *reinterpret_cast<const bf16x8*>(Abuf + (r << 7) + ((ch ^ (r & 7)) << 4));
        }
      if (p == 0) {
#pragma unroll
        for (int nf = 0; nf < 4; ++nf)
#pragma unroll
          for (int ks = 0; ks < 2; ++ks) {
            int r = (wn << 6) + (nf << 4) + lr;
            int ch = (ks << 2) + lk;
            bfr[(nf << 1) + ks] =
                *reinterpret_cast<const bf16x8*>(Bbuf + (r << 7) + ((ch ^ (r & 7)) << 4));
          }
        if (pf) loadA(kt + 1);          // 8 f32x4 loads in flight
      }
      if (p == 1 && pf) stageB(kt + 1); // 4 gload_lds in flight
      if (p == 2 && pf) {
        asm volatile("s_waitcnt vmcnt(4)" ::: "memory");  // A done, B in flight
        writeA(kt + 1, 0);
      }
      if (p == 3 && pf) writeA(kt + 1, 1);
      __builtin_amdgcn_s_barrier();
      __builtin_amdgcn_s_setprio(1);
#pragma unroll
      for (int m2 = 0; m2 < 2; ++m2)
#pragma unroll
        for (int nf = 0; nf < 4; ++nf)
#pragma unroll
          for (int ks = 0; ks < 2; ++ks)
            acc[(p << 1) + m2][nf] = __builtin_amdgcn_mfma_f32_16x16x32_bf16(
                af[(m2 << 1) + ks], bfr[(nf << 1) + ks], acc[(p << 1) + m2][nf], 0, 0, 0);
      __builtin_amdgcn_s_setprio(0);
      __builtin_amdgcn_s_barrier();
    }
    if (pf) {
      asm volatile("s_waitcnt vmcnt(0) lgkmcnt(0)" ::: "memory");  // B landed + A writes done
      __builtin_amdgcn_s_barrier();
    }
  }

  // ---- epilogue: LDS-bounce then coalesced 16B stores (qkv scatter) ----
  char* ep = lds + (w << 14);
  int gc0 = col0 + (wn << 6);
  int part = gc0 >> 9;              // 0=q 1=k 2=v (uniform per wave)
  int hh = (gc0 & 511) >> 6;
  unsigned short* dst = (part == 0) ? oq : (part == 1) ? okk : ov;
  float bvv[4], rbv[4];
#pragma unroll
  for (int nf = 0; nf < 4; ++nf) {
    int cc = (nf << 4) + lr;
    bvv[nf] = bias[gc0 + cc];
    rbv[nf] = (part == 0) ? brw[(gc0 & 511) + cc] : 0.f;
  }
#pragma unroll
  for (int mf = 0; mf < 8; ++mf) {
#pragma unroll
    for (int nf = 0; nf < 4; ++nf) {
      int cc = (nf << 4) + lr;
#pragma unroll
      for (int j = 0; j < 4; ++j) {
        int r = (mf << 4) + ((lane >> 4) << 2) + j;
        float v = acc[mf][nf][j] + bvv[nf];
        if (part == 0) v = v * 0.125f + rbv[nf];
        int byte = (r << 7) + ((((cc >> 3) ^ (r & 7))) << 4) + ((cc & 7) << 1);
        *reinterpret_cast<unsigned short*>(ep + byte) = f2bf(v);
      }
    }
  }
  asm volatile("s_waitcnt lgkmcnt(0)" ::: "memory");
  __builtin_amdgcn_sched_barrier(0);
  int b0 = row0 >> 11;
  size_t base = (size_t)(b0 * 8 + hh) * 2048;
#pragma unroll
  for (int i = 0; i < 16; ++i) {
    int rr = (i << 3) + (lane >> 3);
    int ch = lane & 7;
    int byte = (rr << 7) + ((ch ^ (rr & 7)) << 4);
    u16x8 val = *reinterpret_cast<const u16x8*>(ep + byte);
    int gl = (row0 + (wm << 7) + rr) & 2047;
    *reinterpret_cast<u16x8*>(dst + ((base + gl) << 6) + (ch << 3)) = val;
  }
}

// ---- GEMM2: 256x256, BK=32, quad-buffered, counted-vmcnt (r4 structure) ----
template <int EPI>
__global__ __launch_bounds__(512, 2) void k_gemm256(
    const unsigned short* __restrict__ A,
    const unsigned short* __restrict__ Bt,
    const float* __restrict__ bias,
    const float* __restrict__ brw,
    unsigned short* __restrict__ oq,
    unsigned short* __restrict__ okk,
    unsigned short* __restrict__ ov,
    float* __restrict__ of,
    int Ntiles) {
  __shared__ __align__(128) char lds[131072];

  int cpx = gridDim.x >> 3;
  int bid = (blockIdx.x & 7) * cpx + (blockIdx.x >> 3);
  int bm = bid / Ntiles;
  int bn = bid - bm * Ntiles;
  int row0 = bm << 8;
  int col0 = bn << 8;
  int t = threadIdx.x;
  int lane = t & 63;
  int w = t >> 6;
  int wm = w >> 2;
  int wn = w & 3;
  int lr = lane & 15;
  int lk = lane >> 4;

  const unsigned short* Ab = A + (size_t)row0 * 512;
  const unsigned short* Bb = Bt + (size_t)col0 * 512;

  f32x4 zero = {0.f, 0.f, 0.f, 0.f};
  f32x4 acc[8][4];
#pragma unroll
  for (int i = 0; i < 8; ++i)
#pragma unroll
    for (int j = 0; j < 4; ++j) acc[i][j] = zero;

  auto stage = [&](int kt) {
    int b = kt & 3;
    int k0 = kt << 5;
#pragma unroll
    for (int i = 0; i < 2; ++i) {
      int o = (i << 9) + t;
      int row = o >> 2;
      int slot = o & 3;
      int gk = k0 + ((slot ^ ((row >> 1) & 3)) << 3);
      gload_lds16(Ab + (size_t)row * 512 + gk, lds + (b << 14) + (o << 4));
      gload_lds16(Bb + (size_t)row * 512 + gk, lds + 65536 + (b << 14) + (o << 4));
    }
  };

  auto tile = [&](int kt, bool prefetch) {
    const char* Abuf = lds + ((kt & 3) << 14);
    const char* Bbuf = lds + 65536 + ((kt & 3) << 14);
    bf16x8 af[8], bfs[4];
#pragma unroll
    for (int nf = 0; nf < 4; ++nf) {
      int r = (wn << 6) + (nf << 4) + lr;
      bfs[nf] = *reinterpret_cast<const bf16x8*>(Bbuf + (((r << 2) + (lk ^ ((r >> 1) & 3))) << 4));
    }
#pragma unroll
    for (int mf = 0; mf < 8; ++mf) {
      int r = (wm << 7) + (mf << 4) + lr;
      af[mf] = *reinterpret_cast<const bf16x8*>(Abuf + (((r << 2) + (lk ^ ((r >> 1) & 3))) << 4));
    }
    if (prefetch) stage(kt + 3);
    __builtin_amdgcn_s_setprio(1);
#pragma unroll
    for (int mf = 0; mf < 8; ++mf)
#pragma unroll
      for (int nf = 0; nf < 4; ++nf)
        acc[mf][nf] = __builtin_amdgcn_mfma_f32_16x16x32_bf16(af[mf], bfs[nf], acc[mf][nf], 0, 0, 0);
    __builtin_amdgcn_s_setprio(0);
  };

  stage(0); stage(1); stage(2);
  asm volatile("s_waitcnt vmcnt(8)" ::: "memory");
  __builtin_amdgcn_s_barrier();

#pragma unroll 1
  for (int kt = 0; kt < 13; ++kt) {
    tile(kt, true);
    asm volatile("s_waitcnt vmcnt(8)" ::: "memory");
    __builtin_amdgcn_s_barrier();
  }
  tile(13, false);
  asm volatile("s_waitcnt vmcnt(4)" ::: "memory");
  __builtin_amdgcn_s_barrier();
  tile(14, false);
  asm volatile("s_waitcnt vmcnt(0)" ::: "memory");
  __builtin_amdgcn_s_barrier();
  tile(15, false);
  __builtin_amdgcn_s_barrier();

  if (EPI == 0) {
    char* ep = lds + (w << 14);
    int gc0 = col0 + (wn << 6);
    int part = gc0 >> 9;
    int hh = (gc0 & 511) >> 6;
    unsigned short* dst = (part == 0) ? oq : (part == 1) ? okk : ov;
    float bvv[4], rbv[4];
#pragma unroll
    for (int nf = 0; nf < 4; ++nf) {
      int cc = (nf << 4) + lr;
      bvv[nf] = bias[gc0 + cc];
      rbv[nf] = (part == 0) ? brw[(gc0 & 511) + cc] : 0.f;
    }
#pragma unroll
    for (int mf = 0; mf < 8; ++mf) {
#pragma unroll
      for (int nf = 0; nf < 4; ++nf) {
        int cc = (nf << 4) + lr;
#pragma unroll
        for (int j = 0; j < 4; ++j) {
          int r = (mf << 4) + ((lane >> 4) << 2) + j;
          float v = acc[mf][nf][j] + bvv[nf];
          if (part == 0) v = v * 0.125f + rbv[nf];
          int byte = (r << 7) + ((((cc >> 3) ^ (r & 7))) << 4) + ((cc & 7) << 1);
          *reinterpret_cast<unsigned short*>(ep + byte) = f2bf(v);
        }
      }
    }
    asm volatile("s_waitcnt lgkmcnt(0)" ::: "memory");
    __builtin_amdgcn_sched_barrier(0);
    int b0 = row0 >> 11;
    size_t base = (size_t)(b0 * 8 + hh) * 2048;
#pragma unroll
    for (int i = 0; i < 16; ++i) {
      int rr = (i << 3) + (lane >> 3);
      int ch = lane & 7;
      int byte = (rr << 7) + ((ch ^ (rr & 7)) << 4);
      u16x8 val = *reinterpret_cast<const u16x8*>(ep + byte);
      int gl = (row0 + (wm << 7) + rr) & 2047;
      *reinterpret_cast<u16x8*>(dst + ((base + gl) << 6) + (ch << 3)) = val;
    }
  } else {
#pragma unroll
    for (int mf = 0; mf < 8; ++mf) {
#pragma unroll
      for (int j = 0; j < 4; ++j) {
        int gr = row0 + (wm << 7) + (mf << 4) + ((lane >> 4) << 2) + j;
#pragma unroll
        for (int nf = 0; nf < 4; ++nf) {
          int gc = col0 + (wn << 6) + (nf << 4) + lr;
          of[(size_t)gr * 512 + gc] = acc[mf][nf][j] + bias[gc];
        }
      }
    }
  }
}

// ---------------- banded attention, MFMA version ----------------
__global__ __launch_bounds__(256) void k_attn_mfma(
    const unsigned short* __restrict__ qb,
    const unsigned short* __restrict__ kb,
    const unsigned short* __restrict__ vb,
    unsigned short* __restrict__ zb) {
  __shared__ __align__(128) unsigned short smem[13312];  // Vt[0,6656) P[6656,13312)

  int t = threadIdx.x;
  int bh = blockIdx.x >> 5;
  int l0 = (blockIdx.x & 31) << 6;
  size_t slab = (size_t)bh << 17;

#pragma unroll
  for (int i = 0; i < 3; ++i) {
    int kloc = (i << 5) + (t >> 3);
    int c8 = (t & 7) << 3;
    int kg = l0 - 10 + kloc;
    kg = kg < 0 ? 0 : (kg > 2047 ? 2047 : kg);
    u16x8 v = *reinterpret_cast<const u16x8*>(vb + slab + ((size_t)kg << 6) + c8);
#pragma unroll
    for (int e = 0; e < 8; ++e) smem[(c8 + e) * 104 + kloc] = v[e];
  }

  int lane = t & 63;
  int w = t >> 6;
  int lr = lane & 15;
  int lk = lane >> 4;

  const unsigned short* qp = qb + slab + ((size_t)(l0 + (w << 4) + lr) << 6) + (lk << 3);
  bf16x8 qf0 = *reinterpret_cast<const bf16x8*>(qp);
  bf16x8 qf1 = *reinterpret_cast<const bf16x8*>(qp + 32);

  f32x4 sacc[6];
#pragma unroll
  for (int kt = 0; kt < 6; ++kt) {
    int kl = (kt << 4) + lr;
    int kg = l0 - 10 + kl;
    int kgc = kg < 0 ? 0 : (kg > 2047 ? 2047 : kg);
    const unsigned short* kp = kb + slab + ((size_t)kgc << 6) + (lk << 3);
    bf16x8 kf0 = *reinterpret_cast<const bf16x8*>(kp);
    bf16x8 kf1 = *reinterpret_cast<const bf16x8*>(kp + 32);
    f32x4 z4 = {0.f, 0.f, 0.f, 0.f};
    z4 = __builtin_amdgcn_mfma_f32_16x16x32_bf16(qf0, kf0, z4, 0, 0, 0);
    sacc[kt] = __builtin_amdgcn_mfma_f32_16x16x32_bf16(qf1, kf1, z4, 0, 0, 0);
  }

  int qlb = (w << 4) + (lk << 2);
  float p[6][4];
  float minv[4];
#pragma unroll
  for (int j = 0; j < 4; ++j) {
    int ql = qlb + j;
    float mx = -1e30f;
#pragma unroll
    for (int kt = 0; kt < 6; ++kt) {
      int kl = (kt << 4) + lr;
      int kg = l0 - 10 + kl;
      bool valid = (kl >= ql) && (kl <= ql + 20) && (kg >= 0) && (kg < 2048);
      float sv = valid ? sacc[kt][j] : -1e30f;
      p[kt][j] = sv;
      mx = fmaxf(mx, sv);
    }
    mx = fmaxf(mx, __shfl_xor(mx, 1));
    mx = fmaxf(mx, __shfl_xor(mx, 2));
    mx = fmaxf(mx, __shfl_xor(mx, 4));
    mx = fmaxf(mx, __shfl_xor(mx, 8));
    float sum = 0.f;
#pragma unroll
    for (int kt = 0; kt < 6; ++kt) {
      float e = (p[kt][j] > -1e29f) ? __expf(p[kt][j] - mx) : 0.f;
      p[kt][j] = e;
      sum += e;
    }
    sum += __shfl_xor(sum, 1);
    sum += __shfl_xor(sum, 2);
    sum += __shfl_xor(sum, 4);
    sum += __shfl_xor(sum, 8);
    minv[j] = 1.f / sum;
  }

  unsigned short* P = smem + 6656;
#pragma unroll
  for (int j = 0; j < 4; ++j)
#pragma unroll
    for (int kt = 0; kt < 6; ++kt)
      P[(qlb + j) * 104 + (kt << 4) + lr] = f2bf(p[kt][j]);

  __syncthreads();

  f32x4 zacc[4];
#pragma unroll
  for (int dt = 0; dt < 4; ++dt) zacc[dt] = f32x4{0.f, 0.f, 0.f, 0.f};
  bf16x8 pf[3];
#pragma unroll
  for (int s3 = 0; s3 < 3; ++s3)
    pf[s3] = *reinterpret_cast<const bf16x8*>(P + ((w << 4) + lr) * 104 + (s3 << 5) + (lk << 3));
#pragma unroll
  for (int dt = 0; dt < 4; ++dt) {
#pragma unroll
    for (int s3 = 0; s3 < 3; ++s3) {
      bf16x8 vf = *reinterpret_cast<const bf16x8*>(smem + ((dt << 4) + lr) * 104 + (s3 << 5) + (lk << 3));
      zacc[dt] = __builtin_amdgcn_mfma_f32_16x16x32_bf16(pf[s3], vf, zacc[dt], 0, 0, 0);
    }
  }

  __syncthreads();

  unsigned short* ZL = smem;
#pragma unroll
  for (int dt = 0; dt < 4; ++dt)
#pragma unroll
    for (int j = 0; j < 4; ++j)
      ZL[(qlb + j) * 80 + (dt << 4) + lr] = f2bf(zacc[dt][j] * minv[j]);
  asm volatile("s_waitcnt lgkmcnt(0)" ::: "memory");
  __builtin_amdgcn_sched_barrier(0);

  int b = bh >> 3, h = bh & 7;
#pragma unroll
  for (int i = 0; i < 2; ++i) {
    int rr = (w << 4) + (i << 3) + (lane >> 3);
    int ch = (lane & 7) << 3;
    u16x8 val = *reinterpret_cast<const u16x8*>(ZL + rr * 80 + ch);
    size_t orow = (size_t)(b * 2048 + l0 + rr);
    *reinterpret_cast<u16x8*>(zb + (orow << 9) + (h << 6) + ch) = val;
  }
}

// ---------------- launch ----------------

extern "C" void kernel_launch(void* const* d_in, const int* in_sizes, int n_in,
                              void* d_out, int out_size, void* d_ws, size_t ws_size,
                              hipStream_t stream) {
  (void)in_sizes; (void)n_in; (void)out_size; (void)ws_size;
  const float* x    = (const float*)d_in[0];
  const float* Wqkv = (const float*)d_in[1];
  const float* bqkv = (const float*)d_in[2];
  const float* brw  = (const float*)d_in[3];
  const float* Wout = (const float*)d_in[4];
  const float* bout = (const float*)d_in[5];
  float* out = (float*)d_out;

  char* ws = (char*)d_ws;
  unsigned short* zb  = (unsigned short*)(ws);               // z [32768][512] bf16
  unsigned short* wqT = (unsigned short*)(ws + 33554432);
  unsigned short* woT = (unsigned short*)(ws + 35127296);
  unsigned short* qs  = (unsigned short*)(ws + 35651584);
  unsigned short* kbf = (unsigned short*)(ws + 69206016);
  unsigned short* vbf = (unsigned short*)(ws + 102760448);

  k_cvt_wT<<<768, 256, 0, stream>>>(Wqkv, wqT, 512, 1536);
  k_cvt_wT<<<256, 256, 0, stream>>>(Wout, woT, 512, 512);
  k_g1<<<768, 512, 0, stream>>>(x, wqT, bqkv, brw, qs, kbf, vbf, 6);
  k_attn_mfma<<<4096, 256, 0, stream>>>(qs, kbf, vbf, zb);
  k_gemm256<1><<<256, 512, 0, stream>>>(zb, woT, bout, nullptr, nullptr, nullptr, nullptr, out, 2);
}

// Round 7
// 160.023 us; speedup vs baseline: 1.0740x; 1.0740x over previous
//
#include <hip/hip_runtime.h>
#include <stdint.h>

typedef __bf16 bf16x8 __attribute__((ext_vector_type(8)));
typedef float f32x4 __attribute__((ext_vector_type(4)));
typedef unsigned short u16x8 __attribute__((ext_vector_type(8)));

__device__ __forceinline__ unsigned short f2bf(float f) {
  uint32_t u = __builtin_bit_cast(uint32_t, f);
  u += 0x7FFFu + ((u >> 16) & 1u);   // RNE
  return (unsigned short)(u >> 16);
}
__device__ __forceinline__ float bf2f(unsigned short h) {
  uint32_t u = ((uint32_t)h) << 16;
  return __builtin_bit_cast(float, u);
}

__device__ __forceinline__ void gload_lds16(const void* g, void* l) {
  __builtin_amdgcn_global_load_lds(
      (const __attribute__((address_space(1))) uint32_t*)g,
      (__attribute__((address_space(3))) uint32_t*)l,
      16, 0, 0);
}

// ---------------- convert kernels ----------------

__global__ __launch_bounds__(256) void k_cvt_x(const float* __restrict__ x,
                                               unsigned short* __restrict__ xb, int n4) {
  int stride = gridDim.x * blockDim.x;
  for (int i = blockIdx.x * blockDim.x + threadIdx.x; i < n4; i += stride) {
    float4 v = reinterpret_cast<const float4*>(x)[i];
    ushort4 o;
    o.x = f2bf(v.x); o.y = f2bf(v.y); o.z = f2bf(v.z); o.w = f2bf(v.w);
    reinterpret_cast<ushort4*>(xb)[i] = o;
  }
}

// w: [K][N] f32  ->  wt: [N][K] bf16  (transpose + convert)
__global__ __launch_bounds__(256) void k_cvt_wT(const float* __restrict__ w,
                                                unsigned short* __restrict__ wt, int K, int N) {
  int total = K * N;
  int stride = gridDim.x * blockDim.x;
  for (int i = blockIdx.x * blockDim.x + threadIdx.x; i < total; i += stride) {
    int n = i / K;
    int k = i - n * K;
    wt[i] = f2bf(w[(size_t)k * N + n]);
  }
}

// ---- GEMM 256x256, BK=32, quad-buffered, counted-vmcnt, PHASED (T3+T4+T5)
// C[M,N] = A[M,512] * Bt[N,512]^T. 8 waves (2Mx4N), wave-tile 128x64.
// LDS: 4 buffers x (A 16KB + B 16KB) = 128KB. Stage tile kt+3 during kt.
// Each K-tile = 2 phases:
//   p0: {ds_read B(4xb128) + A mf0-3 ; stage half0 of kt+3 ; s_barrier ;
//        setprio(1) 16 MFMA setprio(0) ; s_barrier}
//   p1: {ds_read A mf4-7 ; stage half1 ; s_barrier ;
//        setprio(1) 16 MFMA setprio(0)}
//   tile end: s_waitcnt vmcnt(8)  (kt+1 complete; kt+2,kt+3 IN FLIGHT across
//   the barrier — never drains to 0 in main loop) ; s_barrier.
// Chunk swizzle slot^=(row>>1)&3 on BOTH stage source and ds_read (rule #21).
// EPI==0: qkv epilogue (bf16 LDS-bounce scatter); EPI==1: f32 C + bias.
template <int EPI>
__global__ __launch_bounds__(512, 2) void k_gemm256(
    const unsigned short* __restrict__ A,
    const unsigned short* __restrict__ Bt,
    const float* __restrict__ bias,
    const float* __restrict__ brw,
    unsigned short* __restrict__ oq,
    unsigned short* __restrict__ okk,
    unsigned short* __restrict__ ov,
    float* __restrict__ of,
    int Ntiles) {
  __shared__ __align__(128) char lds[131072];

  int cpx = gridDim.x >> 3;
  int bid = (blockIdx.x & 7) * cpx + (blockIdx.x >> 3);
  int bm = bid / Ntiles;
  int bn = bid - bm * Ntiles;
  int row0 = bm << 8;
  int col0 = bn << 8;
  int t = threadIdx.x;
  int lane = t & 63;
  int w = t >> 6;        // wave 0..7
  int wm = w >> 2;       // 0..1
  int wn = w & 3;        // 0..3
  int lr = lane & 15;
  int lk = lane >> 4;

  const unsigned short* Ab = A + (size_t)row0 * 512;
  const unsigned short* Bb = Bt + (size_t)col0 * 512;

  f32x4 acc[8][4];
#pragma unroll
  for (int i = 0; i < 8; ++i)
#pragma unroll
    for (int j = 0; j < 4; ++j) acc[i][j] = f32x4{0.f, 0.f, 0.f, 0.f};

  // stage half h (0/1) of K-tile kt into buffer kt&3: 2 gloads/thread
  auto stageHalf = [&](int kt, int h) {
    int b = kt & 3;
    int k0 = kt << 5;
    int o = (h << 9) + t;          // chunk index
    int row = o >> 2;              // 0..255
    int slot = o & 3;
    int gk = k0 + ((slot ^ ((row >> 1) & 3)) << 3);
    gload_lds16(Ab + (size_t)row * 512 + gk, lds + (b << 14) + (o << 4));
    gload_lds16(Bb + (size_t)row * 512 + gk, lds + 65536 + (b << 14) + (o << 4));
  };

  // one K-tile, 2-phase interleave; ends after p1 MFMA (tile-end sync outside)
  auto tileP = [&](int kt, bool pf) {
    const char* Abuf = lds + ((kt & 3) << 14);
    const char* Bbuf = lds + 65536 + ((kt & 3) << 14);
    // ---- phase 0
    bf16x8 bfs[4], af[4];
#pragma unroll
    for (int nf = 0; nf < 4; ++nf) {
      int r = (wn << 6) + (nf << 4) + lr;
      bfs[nf] = *reinterpret_cast<const bf16x8*>(Bbuf + (((r << 2) + (lk ^ ((r >> 1) & 3))) << 4));
    }
#pragma unroll
    for (int mf = 0; mf < 4; ++mf) {
      int r = (wm << 7) + (mf << 4) + lr;
      af[mf] = *reinterpret_cast<const bf16x8*>(Abuf + (((r << 2) + (lk ^ ((r >> 1) & 3))) << 4));
    }
    if (pf) stageHalf(kt + 3, 0);
    __builtin_amdgcn_s_barrier();
    __builtin_amdgcn_s_setprio(1);
#pragma unroll
    for (int mf = 0; mf < 4; ++mf)
#pragma unroll
      for (int nf = 0; nf < 4; ++nf)
        acc[mf][nf] = __builtin_amdgcn_mfma_f32_16x16x32_bf16(af[mf], bfs[nf], acc[mf][nf], 0, 0, 0);
    __builtin_amdgcn_s_setprio(0);
    __builtin_amdgcn_s_barrier();
    // ---- phase 1
    bf16x8 af2[4];
#pragma unroll
    for (int mf = 0; mf < 4; ++mf) {
      int r = (wm << 7) + ((4 + mf) << 4) + lr;
      af2[mf] = *reinterpret_cast<const bf16x8*>(Abuf + (((r << 2) + (lk ^ ((r >> 1) & 3))) << 4));
    }
    if (pf) stageHalf(kt + 3, 1);
    __builtin_amdgcn_s_barrier();
    __builtin_amdgcn_s_setprio(1);
#pragma unroll
    for (int mf = 0; mf < 4; ++mf)
#pragma unroll
      for (int nf = 0; nf < 4; ++nf)
        acc[4 + mf][nf] = __builtin_amdgcn_mfma_f32_16x16x32_bf16(af2[mf], bfs[nf], acc[4 + mf][nf], 0, 0, 0);
    __builtin_amdgcn_s_setprio(0);
  };

  // prologue: stage tiles 0,1,2 (12 loads); wait tile 0 (1,2 in flight)
  stageHalf(0, 0); stageHalf(0, 1);
  stageHalf(1, 0); stageHalf(1, 1);
  stageHalf(2, 0); stageHalf(2, 1);
  asm volatile("s_waitcnt vmcnt(8)" ::: "memory");
  __builtin_amdgcn_s_barrier();

#pragma unroll 1
  for (int kt = 0; kt < 13; ++kt) {
    tileP(kt, true);
    // kt+1's 4 loads are oldest of 12 outstanding; kt+2,kt+3 stay in flight
    asm volatile("s_waitcnt vmcnt(8)" ::: "memory");
    __builtin_amdgcn_s_barrier();
  }
  tileP(13, false);
  asm volatile("s_waitcnt vmcnt(4)" ::: "memory");
  __builtin_amdgcn_s_barrier();
  tileP(14, false);
  asm volatile("s_waitcnt vmcnt(0)" ::: "memory");
  __builtin_amdgcn_s_barrier();
  tileP(15, false);
  __builtin_amdgcn_s_barrier();  // all reads done before epilogue LDS overwrite

  if (EPI == 0) {
    // ---- epilogue: LDS-bounce then coalesced 16B stores (qkv scatter) ----
    char* ep = lds + (w << 14);
    int gc0 = col0 + (wn << 6);
    int part = gc0 >> 9;              // 0=q 1=k 2=v (uniform per wave)
    int hh = (gc0 & 511) >> 6;
    unsigned short* dst = (part == 0) ? oq : (part == 1) ? okk : ov;
    float bvv[4], rbv[4];
#pragma unroll
    for (int nf = 0; nf < 4; ++nf) {
      int cc = (nf << 4) + lr;
      bvv[nf] = bias[gc0 + cc];
      rbv[nf] = (part == 0) ? brw[(gc0 & 511) + cc] : 0.f;
    }
#pragma unroll
    for (int mf = 0; mf < 8; ++mf) {
#pragma unroll
      for (int nf = 0; nf < 4; ++nf) {
        int cc = (nf << 4) + lr;
#pragma unroll
        for (int j = 0; j < 4; ++j) {
          int r = (mf << 4) + ((lane >> 4) << 2) + j;
          float v = acc[mf][nf][j] + bvv[nf];
          if (part == 0) v = v * 0.125f + rbv[nf];
          int byte = (r << 7) + ((((cc >> 3) ^ (r & 7))) << 4) + ((cc & 7) << 1);
          *reinterpret_cast<unsigned short*>(ep + byte) = f2bf(v);
        }
      }
    }
    asm volatile("s_waitcnt lgkmcnt(0)" ::: "memory");
    __builtin_amdgcn_sched_barrier(0);
    int b0 = row0 >> 11;
    size_t base = (size_t)(b0 * 8 + hh) * 2048;
#pragma unroll
    for (int i = 0; i < 16; ++i) {
      int rr = (i << 3) + (lane >> 3);
      int ch = lane & 7;
      int byte = (rr << 7) + ((ch ^ (rr & 7)) << 4);
      u16x8 val = *reinterpret_cast<const u16x8*>(ep + byte);
      int gl = (row0 + (wm << 7) + rr) & 2047;
      *reinterpret_cast<u16x8*>(dst + ((base + gl) << 6) + (ch << 3)) = val;
    }
  } else {
    // ---- epilogue: f32 C + bias, direct stores ----
#pragma unroll
    for (int mf = 0; mf < 8; ++mf) {
#pragma unroll
      for (int j = 0; j < 4; ++j) {
        int gr = row0 + (wm << 7) + (mf << 4) + ((lane >> 4) << 2) + j;
#pragma unroll
        for (int nf = 0; nf < 4; ++nf) {
          int gc = col0 + (wn << 6) + (nf << 4) + lr;
          of[(size_t)gr * 512 + gc] = acc[mf][nf][j] + bias[gc];
        }
      }
    }
  }
}

// ---------------- banded attention, MFMA version ----------------
// q/k/v: [B*H][2048][64] bf16.  z: [32768][512] bf16 (col = h*64+e).
__global__ __launch_bounds__(256) void k_attn_mfma(
    const unsigned short* __restrict__ qb,
    const unsigned short* __restrict__ kb,
    const unsigned short* __restrict__ vb,
    unsigned short* __restrict__ zb) {
  __shared__ __align__(128) unsigned short smem[13312];  // Vt[0,6656) P[6656,13312)

  int t = threadIdx.x;
  int bh = blockIdx.x >> 5;
  int l0 = (blockIdx.x & 31) << 6;
  size_t slab = (size_t)bh << 17;

#pragma unroll
  for (int i = 0; i < 3; ++i) {
    int kloc = (i << 5) + (t >> 3);
    int c8 = (t & 7) << 3;
    int kg = l0 - 10 + kloc;
    kg = kg < 0 ? 0 : (kg > 2047 ? 2047 : kg);
    u16x8 v = *reinterpret_cast<const u16x8*>(vb + slab + ((size_t)kg << 6) + c8);
#pragma unroll
    for (int e = 0; e < 8; ++e) smem[(c8 + e) * 104 + kloc] = v[e];
  }

  int lane = t & 63;
  int w = t >> 6;
  int lr = lane & 15;
  int lk = lane >> 4;

  const unsigned short* qp = qb + slab + ((size_t)(l0 + (w << 4) + lr) << 6) + (lk << 3);
  bf16x8 qf0 = *reinterpret_cast<const bf16x8*>(qp);
  bf16x8 qf1 = *reinterpret_cast<const bf16x8*>(qp + 32);

  f32x4 sacc[6];
#pragma unroll
  for (int kt = 0; kt < 6; ++kt) {
    int kl = (kt << 4) + lr;
    int kg = l0 - 10 + kl;
    int kgc = kg < 0 ? 0 : (kg > 2047 ? 2047 : kg);
    const unsigned short* kp = kb + slab + ((size_t)kgc << 6) + (lk << 3);
    bf16x8 kf0 = *reinterpret_cast<const bf16x8*>(kp);
    bf16x8 kf1 = *reinterpret_cast<const bf16x8*>(kp + 32);
    f32x4 z4 = {0.f, 0.f, 0.f, 0.f};
    z4 = __builtin_amdgcn_mfma_f32_16x16x32_bf16(qf0, kf0, z4, 0, 0, 0);
    sacc[kt] = __builtin_amdgcn_mfma_f32_16x16x32_bf16(qf1, kf1, z4, 0, 0, 0);
  }

  int qlb = (w << 4) + (lk << 2);
  float p[6][4];
  float minv[4];
#pragma unroll
  for (int j = 0; j < 4; ++j) {
    int ql = qlb + j;
    float mx = -1e30f;
#pragma unroll
    for (int kt = 0; kt < 6; ++kt) {
      int kl = (kt << 4) + lr;
      int kg = l0 - 10 + kl;
      bool valid = (kl >= ql) && (kl <= ql + 20) && (kg >= 0) && (kg < 2048);
      float sv = valid ? sacc[kt][j] : -1e30f;
      p[kt][j] = sv;
      mx = fmaxf(mx, sv);
    }
    mx = fmaxf(mx, __shfl_xor(mx, 1));
    mx = fmaxf(mx, __shfl_xor(mx, 2));
    mx = fmaxf(mx, __shfl_xor(mx, 4));
    mx = fmaxf(mx, __shfl_xor(mx, 8));
    float sum = 0.f;
#pragma unroll
    for (int kt = 0; kt < 6; ++kt) {
      float e = (p[kt][j] > -1e29f) ? __expf(p[kt][j] - mx) : 0.f;
      p[kt][j] = e;
      sum += e;
    }
    sum += __shfl_xor(sum, 1);
    sum += __shfl_xor(sum, 2);
    sum += __shfl_xor(sum, 4);
    sum += __shfl_xor(sum, 8);
    minv[j] = 1.f / sum;
  }

  unsigned short* P = smem + 6656;
#pragma unroll
  for (int j = 0; j < 4; ++j)
#pragma unroll
    for (int kt = 0; kt < 6; ++kt)
      P[(qlb + j) * 104 + (kt << 4) + lr] = f2bf(p[kt][j]);

  __syncthreads();

  f32x4 zacc[4];
#pragma unroll
  for (int dt = 0; dt < 4; ++dt) zacc[dt] = f32x4{0.f, 0.f, 0.f, 0.f};
  bf16x8 pf[3];
#pragma unroll
  for (int s3 = 0; s3 < 3; ++s3)
    pf[s3] = *reinterpret_cast<const bf16x8*>(P + ((w << 4) + lr) * 104 + (s3 << 5) + (lk << 3));
#pragma unroll
  for (int dt = 0; dt < 4; ++dt) {
#pragma unroll
    for (int s3 = 0; s3 < 3; ++s3) {
      bf16x8 vf = *reinterpret_cast<const bf16x8*>(smem + ((dt << 4) + lr) * 104 + (s3 << 5) + (lk << 3));
      zacc[dt] = __builtin_amdgcn_mfma_f32_16x16x32_bf16(pf[s3], vf, zacc[dt], 0, 0, 0);
    }
  }

  __syncthreads();

  unsigned short* ZL = smem;
#pragma unroll
  for (int dt = 0; dt < 4; ++dt)
#pragma unroll
    for (int j = 0; j < 4; ++j)
      ZL[(qlb + j) * 80 + (dt << 4) + lr] = f2bf(zacc[dt][j] * minv[j]);
  asm volatile("s_waitcnt lgkmcnt(0)" ::: "memory");
  __builtin_amdgcn_sched_barrier(0);

  int b = bh >> 3, h = bh & 7;
#pragma unroll
  for (int i = 0; i < 2; ++i) {
    int rr = (w << 4) + (i << 3) + (lane >> 3);
    int ch = (lane & 7) << 3;
    u16x8 val = *reinterpret_cast<const u16x8*>(ZL + rr * 80 + ch);
    size_t orow = (size_t)(b * 2048 + l0 + rr);
    *reinterpret_cast<u16x8*>(zb + (orow << 9) + (h << 6) + ch) = val;
  }
}

// ---------------- launch ----------------

extern "C" void kernel_launch(void* const* d_in, const int* in_sizes, int n_in,
                              void* d_out, int out_size, void* d_ws, size_t ws_size,
                              hipStream_t stream) {
  (void)in_sizes; (void)n_in; (void)out_size; (void)ws_size;
  const float* x    = (const float*)d_in[0];
  const float* Wqkv = (const float*)d_in[1];
  const float* bqkv = (const float*)d_in[2];
  const float* brw  = (const float*)d_in[3];
  const float* Wout = (const float*)d_in[4];
  const float* bout = (const float*)d_in[5];
  float* out = (float*)d_out;

  char* ws = (char*)d_ws;
  unsigned short* xb  = (unsigned short*)(ws);
  unsigned short* wqT = (unsigned short*)(ws + 33554432);
  unsigned short* woT = (unsigned short*)(ws + 35127296);
  unsigned short* qs  = (unsigned short*)(ws + 35651584);
  unsigned short* kbf = (unsigned short*)(ws + 69206016);
  unsigned short* vbf = (unsigned short*)(ws + 102760448);
  unsigned short* zb  = xb;  // safe reuse: x_bf only needed by GEMM1

  k_cvt_x<<<2048, 256, 0, stream>>>(x, xb, 16777216 / 4);
  k_cvt_wT<<<768, 256, 0, stream>>>(Wqkv, wqT, 512, 1536);
  k_cvt_wT<<<256, 256, 0, stream>>>(Wout, woT, 512, 512);
  k_gemm256<0><<<768, 512, 0, stream>>>(xb, wqT, bqkv, brw, qs, kbf, vbf, nullptr, 6);
  k_attn_mfma<<<4096, 256, 0, stream>>>(qs, kbf, vbf, zb);
  k_gemm256<1><<<256, 512, 0, stream>>>(zb, woT, bout, nullptr, nullptr, nullptr, nullptr, out, 2);
}

// Round 8
// 153.378 us; speedup vs baseline: 1.1205x; 1.0433x over previous
//
#include <hip/hip_runtime.h>
#include <stdint.h>

typedef __bf16 bf16x8 __attribute__((ext_vector_type(8)));
typedef float f32x4 __attribute__((ext_vector_type(4)));
typedef unsigned short u16x8 __attribute__((ext_vector_type(8)));

__device__ __forceinline__ unsigned short f2bf(float f) {
  uint32_t u = __builtin_bit_cast(uint32_t, f);
  u += 0x7FFFu + ((u >> 16) & 1u);   // RNE
  return (unsigned short)(u >> 16);
}
__device__ __forceinline__ float bf2f(unsigned short h) {
  uint32_t u = ((uint32_t)h) << 16;
  return __builtin_bit_cast(float, u);
}

__device__ __forceinline__ void gload_lds16(const void* g, void* l) {
  __builtin_amdgcn_global_load_lds(
      (const __attribute__((address_space(1))) uint32_t*)g,
      (__attribute__((address_space(3))) uint32_t*)l,
      16, 0, 0);
}

// ---------------- convert kernels ----------------

__global__ __launch_bounds__(256) void k_cvt_x(const float* __restrict__ x,
                                               unsigned short* __restrict__ xb, int n4) {
  int stride = gridDim.x * blockDim.x;
  for (int i = blockIdx.x * blockDim.x + threadIdx.x; i < n4; i += stride) {
    float4 v = reinterpret_cast<const float4*>(x)[i];
    ushort4 o;
    o.x = f2bf(v.x); o.y = f2bf(v.y); o.z = f2bf(v.z); o.w = f2bf(v.w);
    reinterpret_cast<ushort4*>(xb)[i] = o;
  }
}

// w: [K][N] f32  ->  wt: [N][K] bf16  (transpose + convert)
__global__ __launch_bounds__(256) void k_cvt_wT(const float* __restrict__ w,
                                                unsigned short* __restrict__ wt, int K, int N) {
  int total = K * N;
  int stride = gridDim.x * blockDim.x;
  for (int i = blockIdx.x * blockDim.x + threadIdx.x; i < total; i += stride) {
    int n = i / K;
    int k = i - n * K;
    wt[i] = f2bf(w[(size_t)k * N + n]);
  }
}

// ---- GEMM 128x128, BK=32, TRIPLE-buffered, counted-vmcnt, HIGH OCCUPANCY
// C[M,N] = A[M,512] * Bt[N,512]^T. 4 waves (2Mx2N), wave-tile 64x64.
// LDS: 3 buffers x (A 8KB + B 8KB) = 48KB  ->  3 blocks/CU = 12 waves/CU
// = 3 waves/SIMD (occupancy experiment: TLP covers barrier/waitcnt bubbles
// that 2-wave/SIMD schedules could not hide; m114 mechanism).
// Stage tile kt+2 during kt; tile-end s_waitcnt vmcnt(4) (kt+1 complete,
// kt+2 stays in flight across the barrier) + one s_barrier. 16 K-tiles.
// Chunk swizzle slot^=(row>>1)&3 on BOTH stage source and ds_read (rule #21):
// 2 lanes/bank-quad on ds_read_b128 = conflict-free.
// EPI==0: qkv epilogue (bf16 LDS-bounce scatter); EPI==1: f32 C + bias.
template <int EPI>
__global__ __launch_bounds__(256, 3) void k_gemm128(
    const unsigned short* __restrict__ A,
    const unsigned short* __restrict__ Bt,
    const float* __restrict__ bias,
    const float* __restrict__ brw,
    unsigned short* __restrict__ oq,
    unsigned short* __restrict__ okk,
    unsigned short* __restrict__ ov,
    float* __restrict__ of,
    int Ntiles) {
  __shared__ __align__(128) char lds[49152];  // buf b: A at b*16K, B at +8K

  int cpx = gridDim.x >> 3;
  int bid = (blockIdx.x & 7) * cpx + (blockIdx.x >> 3);
  int bm = bid / Ntiles;
  int bn = bid - bm * Ntiles;
  int row0 = bm << 7;
  int col0 = bn << 7;
  int t = threadIdx.x;
  int lane = t & 63;
  int w = t >> 6;        // wave 0..3
  int wm = w >> 1;       // 0..1
  int wn = w & 1;        // 0..1
  int lr = lane & 15;
  int lk = lane >> 4;    // k-chunk 0..3 (BK=32: 4 x 16B chunks per row)

  const unsigned short* Ab = A + (size_t)row0 * 512;
  const unsigned short* Bb = Bt + (size_t)col0 * 512;

  f32x4 acc[4][4];
#pragma unroll
  for (int i = 0; i < 4; ++i)
#pragma unroll
    for (int j = 0; j < 4; ++j) acc[i][j] = f32x4{0.f, 0.f, 0.f, 0.f};

  // stage K-tile kt into buffer b: 4 gloads/thread (2 A + 2 B)
  auto stage = [&](int kt, int b) {
    int k0 = kt << 5;
    char* base = lds + (b << 14);
#pragma unroll
    for (int i = 0; i < 2; ++i) {
      int o = (i << 8) + t;          // chunk 0..511
      int row = o >> 2;              // 0..127
      int slot = o & 3;
      int gk = k0 + ((slot ^ ((row >> 1) & 3)) << 3);
      gload_lds16(Ab + (size_t)row * 512 + gk, base + (o << 4));
      gload_lds16(Bb + (size_t)row * 512 + gk, base + 8192 + (o << 4));
    }
  };

  // compute K-tile in buffer b (8 ds_read_b128 + 16 MFMA), maybe stage kt+2
  auto tile = [&](int b, int ktpf, int bpf, bool pf) {
    const char* Abuf = lds + (b << 14);
    const char* Bbuf = Abuf + 8192;
    bf16x8 af[4], bfs[4];
#pragma unroll
    for (int nf = 0; nf < 4; ++nf) {
      int r = (wn << 6) + (nf << 4) + lr;
      bfs[nf] = *reinterpret_cast<const bf16x8*>(Bbuf + (r << 6) + ((lk ^ ((r >> 1) & 3)) << 4));
    }
#pragma unroll
    for (int mf = 0; mf < 4; ++mf) {
      int r = (wm << 6) + (mf << 4) + lr;
      af[mf] = *reinterpret_cast<const bf16x8*>(Abuf + (r << 6) + ((lk ^ ((r >> 1) & 3)) << 4));
    }
    if (pf) stage(ktpf, bpf);
    __builtin_amdgcn_s_setprio(1);
#pragma unroll
    for (int mf = 0; mf < 4; ++mf)
#pragma unroll
      for (int nf = 0; nf < 4; ++nf)
        acc[mf][nf] = __builtin_amdgcn_mfma_f32_16x16x32_bf16(af[mf], bfs[nf], acc[mf][nf], 0, 0, 0);
    __builtin_amdgcn_s_setprio(0);
  };

  // prologue: stage tiles 0,1; wait tile 0 (tile 1 in flight)
  stage(0, 0);
  stage(1, 1);
  asm volatile("s_waitcnt vmcnt(4)" ::: "memory");
  __builtin_amdgcn_s_barrier();

  int cb = 0;
#pragma unroll 1
  for (int kt = 0; kt < 14; ++kt) {
    int pb = cb + 2; if (pb >= 3) pb -= 3;
    tile(cb, kt + 2, pb, true);
    // kt+1's 4 loads are oldest of 8 outstanding; kt+2 stays in flight
    asm volatile("s_waitcnt vmcnt(4)" ::: "memory");
    __builtin_amdgcn_s_barrier();
    ++cb; if (cb >= 3) cb -= 3;
  }
  tile(cb, 0, 0, false);               // kt = 14
  asm volatile("s_waitcnt vmcnt(0)" ::: "memory");
  __builtin_amdgcn_s_barrier();
  ++cb; if (cb >= 3) cb -= 3;
  tile(cb, 0, 0, false);               // kt = 15
  __builtin_amdgcn_s_barrier();        // all reads done before LDS reuse

  if (EPI == 0) {
    // ---- epilogue: LDS-bounce (8KB/wave) then coalesced 16B stores ----
    char* ep = lds + (w << 13);        // [64 rows][64 cols] bf16, chunk-XOR
    int gc0 = col0 + (wn << 6);
    int part = gc0 >> 9;               // 0=q 1=k 2=v (uniform per wave)
    int hh = (gc0 & 511) >> 6;
    unsigned short* dst = (part == 0) ? oq : (part == 1) ? okk : ov;
    float bvv[4], rbv[4];
#pragma unroll
    for (int nf = 0; nf < 4; ++nf) {
      int cc = (nf << 4) + lr;
      bvv[nf] = bias[gc0 + cc];
      rbv[nf] = (part == 0) ? brw[(gc0 & 511) + cc] : 0.f;
    }
#pragma unroll
    for (int mf = 0; mf < 4; ++mf) {
#pragma unroll
      for (int nf = 0; nf < 4; ++nf) {
        int cc = (nf << 4) + lr;
#pragma unroll
        for (int j = 0; j < 4; ++j) {
          int r = (mf << 4) + (lk << 2) + j;   // 0..63 within wave rows
          float v = acc[mf][nf][j] + bvv[nf];
          if (part == 0) v = v * 0.125f + rbv[nf];
          int byte = (r << 7) + ((((cc >> 3) ^ (r & 7))) << 4) + ((cc & 7) << 1);
          *reinterpret_cast<unsigned short*>(ep + byte) = f2bf(v);
        }
      }
    }
    asm volatile("s_waitcnt lgkmcnt(0)" ::: "memory");
    __builtin_amdgcn_sched_barrier(0);
    int b0 = row0 >> 11;
    size_t base = (size_t)(b0 * 8 + hh) * 2048;
#pragma unroll
    for (int i = 0; i < 8; ++i) {
      int rr = (i << 3) + (lane >> 3);
      int ch = lane & 7;
      int byte = (rr << 7) + ((ch ^ (rr & 7)) << 4);
      u16x8 val = *reinterpret_cast<const u16x8*>(ep + byte);
      int gl = (row0 + (wm << 6) + rr) & 2047;
      *reinterpret_cast<u16x8*>(dst + ((base + gl) << 6) + (ch << 3)) = val;
    }
  } else {
    // ---- epilogue: f32 C + bias, direct stores ----
#pragma unroll
    for (int mf = 0; mf < 4; ++mf) {
#pragma unroll
      for (int j = 0; j < 4; ++j) {
        int gr = row0 + (wm << 6) + (mf << 4) + (lk << 2) + j;
#pragma unroll
        for (int nf = 0; nf < 4; ++nf) {
          int gc = col0 + (wn << 6) + (nf << 4) + lr;
          of[(size_t)gr * 512 + gc] = acc[mf][nf][j] + bias[gc];
        }
      }
    }
  }
}

// ---------------- banded attention, MFMA version ----------------
// q/k/v: [B*H][2048][64] bf16.  z: [32768][512] bf16 (col = h*64+e).
__global__ __launch_bounds__(256) void k_attn_mfma(
    const unsigned short* __restrict__ qb,
    const unsigned short* __restrict__ kb,
    const unsigned short* __restrict__ vb,
    unsigned short* __restrict__ zb) {
  __shared__ __align__(128) unsigned short smem[13312];  // Vt[0,6656) P[6656,13312)

  int t = threadIdx.x;
  int bh = blockIdx.x >> 5;
  int l0 = (blockIdx.x & 31) << 6;
  size_t slab = (size_t)bh << 17;

#pragma unroll
  for (int i = 0; i < 3; ++i) {
    int kloc = (i << 5) + (t >> 3);
    int c8 = (t & 7) << 3;
    int kg = l0 - 10 + kloc;
    kg = kg < 0 ? 0 : (kg > 2047 ? 2047 : kg);
    u16x8 v = *reinterpret_cast<const u16x8*>(vb + slab + ((size_t)kg << 6) + c8);
#pragma unroll
    for (int e = 0; e < 8; ++e) smem[(c8 + e) * 104 + kloc] = v[e];
  }

  int lane = t & 63;
  int w = t >> 6;
  int lr = lane & 15;
  int lk = lane >> 4;

  const unsigned short* qp = qb + slab + ((size_t)(l0 + (w << 4) + lr) << 6) + (lk << 3);
  bf16x8 qf0 = *reinterpret_cast<const bf16x8*>(qp);
  bf16x8 qf1 = *reinterpret_cast<const bf16x8*>(qp + 32);

  f32x4 sacc[6];
#pragma unroll
  for (int kt = 0; kt < 6; ++kt) {
    int kl = (kt << 4) + lr;
    int kg = l0 - 10 + kl;
    int kgc = kg < 0 ? 0 : (kg > 2047 ? 2047 : kg);
    const unsigned short* kp = kb + slab + ((size_t)kgc << 6) + (lk << 3);
    bf16x8 kf0 = *reinterpret_cast<const bf16x8*>(kp);
    bf16x8 kf1 = *reinterpret_cast<const bf16x8*>(kp + 32);
    f32x4 z4 = {0.f, 0.f, 0.f, 0.f};
    z4 = __builtin_amdgcn_mfma_f32_16x16x32_bf16(qf0, kf0, z4, 0, 0, 0);
    sacc[kt] = __builtin_amdgcn_mfma_f32_16x16x32_bf16(qf1, kf1, z4, 0, 0, 0);
  }

  int qlb = (w << 4) + (lk << 2);
  float p[6][4];
  float minv[4];
#pragma unroll
  for (int j = 0; j < 4; ++j) {
    int ql = qlb + j;
    float mx = -1e30f;
#pragma unroll
    for (int kt = 0; kt < 6; ++kt) {
      int kl = (kt << 4) + lr;
      int kg = l0 - 10 + kl;
      bool valid = (kl >= ql) && (kl <= ql + 20) && (kg >= 0) && (kg < 2048);
      float sv = valid ? sacc[kt][j] : -1e30f;
      p[kt][j] = sv;
      mx = fmaxf(mx, sv);
    }
    mx = fmaxf(mx, __shfl_xor(mx, 1));
    mx = fmaxf(mx, __shfl_xor(mx, 2));
    mx = fmaxf(mx, __shfl_xor(mx, 4));
    mx = fmaxf(mx, __shfl_xor(mx, 8));
    float sum = 0.f;
#pragma unroll
    for (int kt = 0; kt < 6; ++kt) {
      float e = (p[kt][j] > -1e29f) ? __expf(p[kt][j] - mx) : 0.f;
      p[kt][j] = e;
      sum += e;
    }
    sum += __shfl_xor(sum, 1);
    sum += __shfl_xor(sum, 2);
    sum += __shfl_xor(sum, 4);
    sum += __shfl_xor(sum, 8);
    minv[j] = 1.f / sum;
  }

  unsigned short* P = smem + 6656;
#pragma unroll
  for (int j = 0; j < 4; ++j)
#pragma unroll
    for (int kt = 0; kt < 6; ++kt)
      P[(qlb + j) * 104 + (kt << 4) + lr] = f2bf(p[kt][j]);

  __syncthreads();

  f32x4 zacc[4];
#pragma unroll
  for (int dt = 0; dt < 4; ++dt) zacc[dt] = f32x4{0.f, 0.f, 0.f, 0.f};
  bf16x8 pf[3];
#pragma unroll
  for (int s3 = 0; s3 < 3; ++s3)
    pf[s3] = *reinterpret_cast<const bf16x8*>(P + ((w << 4) + lr) * 104 + (s3 << 5) + (lk << 3));
#pragma unroll
  for (int dt = 0; dt < 4; ++dt) {
#pragma unroll
    for (int s3 = 0; s3 < 3; ++s3) {
      bf16x8 vf = *reinterpret_cast<const bf16x8*>(smem + ((dt << 4) + lr) * 104 + (s3 << 5) + (lk << 3));
      zacc[dt] = __builtin_amdgcn_mfma_f32_16x16x32_bf16(pf[s3], vf, zacc[dt], 0, 0, 0);
    }
  }

  __syncthreads();

  unsigned short* ZL = smem;
#pragma unroll
  for (int dt = 0; dt < 4; ++dt)
#pragma unroll
    for (int j = 0; j < 4; ++j)
      ZL[(qlb + j) * 80 + (dt << 4) + lr] = f2bf(zacc[dt][j] * minv[j]);
  asm volatile("s_waitcnt lgkmcnt(0)" ::: "memory");
  __builtin_amdgcn_sched_barrier(0);

  int b = bh >> 3, h = bh & 7;
#pragma unroll
  for (int i = 0; i < 2; ++i) {
    int rr = (w << 4) + (i << 3) + (lane >> 3);
    int ch = (lane & 7) << 3;
    u16x8 val = *reinterpret_cast<const u16x8*>(ZL + rr * 80 + ch);
    size_t orow = (size_t)(b * 2048 + l0 + rr);
    *reinterpret_cast<u16x8*>(zb + (orow << 9) + (h << 6) + ch) = val;
  }
}

// ---------------- launch ----------------

extern "C" void kernel_launch(void* const* d_in, const int* in_sizes, int n_in,
                              void* d_out, int out_size, void* d_ws, size_t ws_size,
                              hipStream_t stream) {
  (void)in_sizes; (void)n_in; (void)out_size; (void)ws_size;
  const float* x    = (const float*)d_in[0];
  const float* Wqkv = (const float*)d_in[1];
  const float* bqkv = (const float*)d_in[2];
  const float* brw  = (const float*)d_in[3];
  const float* Wout = (const float*)d_in[4];
  const float* bout = (const float*)d_in[5];
  float* out = (float*)d_out;

  char* ws = (char*)d_ws;
  unsigned short* xb  = (unsigned short*)(ws);
  unsigned short* wqT = (unsigned short*)(ws + 33554432);
  unsigned short* woT = (unsigned short*)(ws + 35127296);
  unsigned short* qs  = (unsigned short*)(ws + 35651584);
  unsigned short* kbf = (unsigned short*)(ws + 69206016);
  unsigned short* vbf = (unsigned short*)(ws + 102760448);
  unsigned short* zb  = xb;  // safe reuse: x_bf only needed by GEMM1

  k_cvt_x<<<2048, 256, 0, stream>>>(x, xb, 16777216 / 4);
  k_cvt_wT<<<768, 256, 0, stream>>>(Wqkv, wqT, 512, 1536);
  k_cvt_wT<<<256, 256, 0, stream>>>(Wout, woT, 512, 512);
  k_gemm128<0><<<3072, 256, 0, stream>>>(xb, wqT, bqkv, brw, qs, kbf, vbf, nullptr, 12);
  k_attn_mfma<<<4096, 256, 0, stream>>>(qs, kbf, vbf, zb);
  k_gemm128<1><<<1024, 256, 0, stream>>>(zb, woT, bout, nullptr, nullptr, nullptr, nullptr, out, 4);
}